// Round 3
// baseline (1909.409 us; speedup 1.0000x reference)
//
#include <hip/hip_runtime.h>
#include <hip/hip_bf16.h>
#include <math.h>

// Problem constants
#define BB    16
#define LS    256
#define LT    128
#define EMB   128
#define HID   256
#define G4    1024      // 4*HID
#define VOCAB 32000

// LSTM slicing: 8 slice-WGs per batch, each owns 32 hidden units (128 gate cols)
#define NSL   8

typedef __attribute__((ext_vector_type(8))) short bf16x8;
typedef __attribute__((ext_vector_type(4))) float f32x4;
typedef __attribute__((ext_vector_type(4))) int   i32x4;
typedef unsigned short ushort_t;
typedef unsigned int uint_t;

__device__ inline float sigf(float x)      { return 1.0f / (1.0f + __expf(-x)); }
__device__ inline float tanhfast(float x)  { return 1.0f - 2.0f / (1.0f + __expf(2.0f * x)); }
__device__ inline ushort_t bf16_rne(float f) {
  __hip_bfloat16 h = __float2bfloat16(f);
  return *(ushort_t*)&h;
}

// ---------------------------------------------------------------------------
// Kernel 1: xz = emb[idx] @ Wk + b.  32 rows/WG to cut Wk re-reads.
// ---------------------------------------------------------------------------
__global__ __launch_bounds__(256) void embed_proj_kernel(
    const int* __restrict__ idx, const float* __restrict__ emb,
    const float* __restrict__ Wk, const float* __restrict__ bias,
    float* __restrict__ xz)
{
  __shared__ float e[32][EMB];    // 16 KB
  const int row0 = blockIdx.x * 32;
  const int tid = threadIdx.x;

  for (int i = tid; i < 32 * EMB; i += 256) {
    int r = i >> 7, k = i & 127;
    int token = idx[row0 + r];
    e[r][k] = emb[(size_t)token * EMB + k];
  }
  __syncthreads();

  float acc[4][32];
#pragma unroll
  for (int q = 0; q < 4; ++q)
#pragma unroll
    for (int r = 0; r < 32; ++r) acc[q][r] = 0.0f;

  for (int k = 0; k < EMB; ++k) {
    float w0 = Wk[(size_t)k * G4 + 0 * 256 + tid];
    float w1 = Wk[(size_t)k * G4 + 1 * 256 + tid];
    float w2 = Wk[(size_t)k * G4 + 2 * 256 + tid];
    float w3 = Wk[(size_t)k * G4 + 3 * 256 + tid];
#pragma unroll
    for (int r = 0; r < 32; ++r) {
      float ev = e[r][k];
      acc[0][r] = fmaf(ev, w0, acc[0][r]);
      acc[1][r] = fmaf(ev, w1, acc[1][r]);
      acc[2][r] = fmaf(ev, w2, acc[2][r]);
      acc[3][r] = fmaf(ev, w3, acc[3][r]);
    }
  }
#pragma unroll
  for (int q = 0; q < 4; ++q) {
    float bb = bias[q * 256 + tid];
#pragma unroll
    for (int r = 0; r < 32; ++r)
      xz[(size_t)(row0 + r) * G4 + q * 256 + tid] = acc[q][r] + bb;
  }
}

// ---------------------------------------------------------------------------
// Kernel 2: LSTM recurrence, 8 slice-WGs per batch (128 WGs).
// Checksummed mailbox chunks {h0,h1,h0^h1^(t+1),0}: one poll load returns
// data + validity. Torn reads either fail checksum (retry) or are
// value-correct. Zeroed mailbox never validates (stamp t+1 != 0).
// ---------------------------------------------------------------------------
__global__ __launch_bounds__(256, 1) void lstm_kernel(
    const float* __restrict__ xz,    // [B*T, 1024]
    const float* __restrict__ Wr,    // [256, 1024]
    const float* __restrict__ h0,    // null => zeros; row stride h0_stride
    int h0_stride,
    const float* __restrict__ cinit, // null => zeros; [B,256]
    float* __restrict__ Hout,        // [B*T, 256]
    float* __restrict__ c_fin,       // [B, 256] or null
    i32x4* __restrict__ mbox,        // [B*T*128] chunks, zeroed at launch
    int T)
{
  const int b    = blockIdx.x & (BB - 1);
  const int s    = blockIdx.x >> 4;
  const int tid  = threadIdx.x;
  const int lane = tid & 63;
  const int half = tid >> 7;           // 0: h[0..127], 1: h[128..255]
  const int col  = tid & 127;          // gate col within slice
  const int gate = col >> 5, u = col & 31;

  __shared__ float part[2][128];

  // weight column slice in registers: w_r[j] = Wr[half*128+j][gate*256+s*32+u]
  float w_r[128];
  {
    const float* wp = Wr + (size_t)(half * 128) * G4 + gate * 256 + s * 32 + u;
#pragma unroll
    for (int j = 0; j < 128; ++j) w_r[j] = wp[(size_t)j * G4];
  }

  // h layout for readlane dot: hv0 = h[half*128+lane], hv1 = h[half*128+64+lane]
  const int i0 = half * 128 + lane;
  float hv0 = 0.0f, hv1 = 0.0f;
  if (h0) {
    hv0 = h0[(size_t)b * h0_stride + i0];
    hv1 = h0[(size_t)b * h0_stride + i0 + 64];
  }
  // cell state: threads 0..15 carry 2 adjacent units each
  float cs0 = 0.0f, cs1 = 0.0f;
  if (tid < 16 && cinit) {
    cs0 = cinit[b * HID + s * 32 + 2 * tid];
    cs1 = cinit[b * HID + s * 32 + 2 * tid + 1];
  }

  const int c0i = i0 >> 1;         // chunk for hv0 (c1i = c0i+32)
  const int sel = i0 & 1;

  for (int t = 0; t < T; ++t) {
    // prefetch xz for pointwise (threads 0..15, 2 units each, 4 gates)
    float2 xg0, xg1, xg2, xg3;
    if (tid < 16) {
      const float* xp = xz + ((size_t)b * T + t) * G4 + s * 32 + 2 * tid;
      xg0 = *(const float2*)(xp);
      xg1 = *(const float2*)(xp + 256);
      xg2 = *(const float2*)(xp + 512);
      xg3 = *(const float2*)(xp + 768);
    }

    // partial dot over this half's 128 h values
    float acc = 0.0f;
#pragma unroll
    for (int j = 0; j < 64; ++j) {
      float sa = __int_as_float(__builtin_amdgcn_readlane(__float_as_int(hv0), j));
      acc = fmaf(sa, w_r[j], acc);
    }
#pragma unroll
    for (int j = 0; j < 64; ++j) {
      float sb = __int_as_float(__builtin_amdgcn_readlane(__float_as_int(hv1), j));
      acc = fmaf(sb, w_r[64 + j], acc);
    }
    part[half][col] = acc;
    __syncthreads();

    // pointwise: thread q<16 computes units 2q, 2q+1; writes Hout + mailbox chunk
    if (tid < 16) {
      const int ua = 2 * tid, ub = ua + 1;
      float zi0 = part[0][ua]      + part[1][ua]      + xg0.x;
      float zi1 = part[0][ub]      + part[1][ub]      + xg0.y;
      float zf0 = part[0][32 + ua] + part[1][32 + ua] + xg1.x;
      float zf1 = part[0][32 + ub] + part[1][32 + ub] + xg1.y;
      float zg0 = part[0][64 + ua] + part[1][64 + ua] + xg2.x;
      float zg1 = part[0][64 + ub] + part[1][64 + ub] + xg2.y;
      float zo0 = part[0][96 + ua] + part[1][96 + ua] + xg3.x;
      float zo1 = part[0][96 + ub] + part[1][96 + ub] + xg3.y;

      cs0 = fmaf(sigf(zf0), cs0, sigf(zi0) * tanhfast(zg0));
      cs1 = fmaf(sigf(zf1), cs1, sigf(zi1) * tanhfast(zg1));
      float ha = sigf(zo0) * tanhfast(cs0);
      float hb = sigf(zo1) * tanhfast(cs1);

      *(float2*)&Hout[((size_t)b * T + t) * HID + s * 32 + ua] = make_float2(ha, hb);

      i32x4 ch;
      ch.x = __float_as_int(ha);
      ch.y = __float_as_int(hb);
      ch.z = ch.x ^ ch.y ^ (t + 1);
      ch.w = 0;
      const i32x4* dst = mbox + ((size_t)b * T + t) * 128 + (s * 16 + tid);
      asm volatile("global_store_dwordx4 %0, %1, off sc0 sc1"
                   :: "v"(dst), "v"(ch) : "memory");
    }

    // poll next h: each thread needs chunks c0i and c0i+32 of slot t
    if (t + 1 < T) {
      const i32x4* pa = mbox + ((size_t)b * T + t) * 128 + c0i;
      const i32x4* pb = pa + 32;
      const int stamp = t + 1;
      i32x4 va, vb;
      for (;;) {
        asm volatile(
            "global_load_dwordx4 %0, %2, off sc0 sc1\n\t"
            "global_load_dwordx4 %1, %3, off sc0 sc1\n\t"
            "s_waitcnt vmcnt(0)"
            : "=&v"(va), "=&v"(vb)
            : "v"(pa), "v"(pb)
            : "memory");
        if ((va.z == (va.x ^ va.y ^ stamp)) && (vb.z == (vb.x ^ vb.y ^ stamp)))
          break;
      }
      hv0 = __int_as_float(sel ? va.y : va.x);
      hv1 = __int_as_float(sel ? vb.y : vb.x);
    }
  }
  if (c_fin && tid < 16)
    *(float2*)&c_fin[b * HID + s * 32 + 2 * tid] = make_float2(cs0, cs1);
}

// ---------------------------------------------------------------------------
// Kernel 3: attention + feat pack -> featB (bf16 [M=2048][K=512]).
// ---------------------------------------------------------------------------
__global__ __launch_bounds__(256) void attn_kernel(
    const float* __restrict__ Henc, const float* __restrict__ S,
    __hip_bfloat16* __restrict__ featB)
{
  const int m = blockIdx.x;          // b*LT + t
  const int b = m >> 7, t = m & (LT - 1);
  const int tid = threadIdx.x;

  __shared__ float srow[HID];
  __shared__ float p[LS];
  __shared__ float sm[LS];

  const float* s_ = (t == 0) ? (Henc + ((size_t)b * LS + (LS - 1)) * HID)
                             : (S + (size_t)(m - 1) * HID);
  srow[tid] = s_[tid];
  __syncthreads();

  const float4* h4 = (const float4*)(Henc + ((size_t)b * LS + tid) * HID);
  const float4* s4 = (const float4*)srow;
  float sc = 0.0f;
#pragma unroll 8
  for (int k = 0; k < HID / 4; ++k) {
    float4 a = h4[k], q = s4[k];
    sc += a.x * q.x + a.y * q.y + a.z * q.z + a.w * q.w;
  }
  sm[tid] = sc;
  __syncthreads();
  for (int st = 128; st > 0; st >>= 1) {
    if (tid < st) sm[tid] = fmaxf(sm[tid], sm[tid + st]);
    __syncthreads();
  }
  float mx = sm[0];
  __syncthreads();
  float e = __expf(sc - mx);
  p[tid] = e;
  sm[tid] = e;
  __syncthreads();
  for (int st = 128; st > 0; st >>= 1) {
    if (tid < st) sm[tid] += sm[tid + st];
    __syncthreads();
  }
  float inv = 1.0f / sm[0];

  float a_d = 0.0f;
#pragma unroll 4
  for (int s2 = 0; s2 < LS; ++s2)
    a_d = fmaf(p[s2], Henc[((size_t)b * LS + s2) * HID + tid], a_d);
  a_d *= inv;

  featB[(size_t)m * (2 * HID) + tid]       = __float2bfloat16(S[(size_t)m * HID + tid]);
  featB[(size_t)m * (2 * HID) + HID + tid] = __float2bfloat16(a_d);
}

// ---------------------------------------------------------------------------
// Kernel 4: prepack WoutT[n][k] = bf16(Wout[k][n]). 64x64 tiles via LDS.
// ---------------------------------------------------------------------------
__global__ __launch_bounds__(256) void prepack_wt_kernel(
    const float* __restrict__ W, ushort_t* __restrict__ WT)
{
  __shared__ float tile[64][65];
  const int nt = blockIdx.x % 500;
  const int kt = blockIdx.x / 500;
  const int n0 = nt * 64, k0 = kt * 64;
  const int tid = threadIdx.x;
  const int r = tid >> 6, c = tid & 63;

#pragma unroll
  for (int q = 0; q < 16; ++q) {
    int kk = q * 4 + r;
    tile[kk][c] = W[(size_t)(k0 + kk) * VOCAB + n0 + c];
  }
  __syncthreads();

  const int nl = tid >> 2;             // 0..63 output row
  const int seg = (tid & 3) * 16;      // 16 k per thread
  uint_t o[8];
#pragma unroll
  for (int j = 0; j < 8; ++j) {
    uint_t lo = bf16_rne(tile[seg + 2 * j][nl]);
    uint_t hi = bf16_rne(tile[seg + 2 * j + 1][nl]);
    o[j] = lo | (hi << 16);
  }
  ushort_t* dst = WT + (size_t)(n0 + nl) * 512 + k0 + seg;
  ((uint4*)dst)[0] = make_uint4(o[0], o[1], o[2], o[3]);
  ((uint4*)dst)[1] = make_uint4(o[4], o[5], o[6], o[7]);
}

// ---------------------------------------------------------------------------
// GEMM core: 256x128 tile, 4 waves (2x2), wave tile 128x64, direct loads.
// ---------------------------------------------------------------------------
__device__ inline void gemm_tile(
    const ushort_t* __restrict__ A, const ushort_t* __restrict__ BT,
    f32x4 (&acc)[8][4], int m0, int n0, int r, int kg)
{
#pragma unroll
  for (int i = 0; i < 8; ++i)
#pragma unroll
    for (int j = 0; j < 4; ++j) acc[i][j] = (f32x4){0.f, 0.f, 0.f, 0.f};

  for (int ks = 0; ks < 16; ++ks) {
    const int kb = ks * 32 + kg * 8;
    bf16x8 a[8], bb[4];
#pragma unroll
    for (int i = 0; i < 8; ++i)
      a[i] = *(const bf16x8*)(A + (size_t)(m0 + i * 16 + r) * 512 + kb);
#pragma unroll
    for (int j = 0; j < 4; ++j)
      bb[j] = *(const bf16x8*)(BT + (size_t)(n0 + j * 16 + r) * 512 + kb);
#pragma unroll
    for (int i = 0; i < 8; ++i)
#pragma unroll
      for (int j = 0; j < 4; ++j)
        acc[i][j] = __builtin_amdgcn_mfma_f32_16x16x32_bf16(a[i], bb[j], acc[i][j], 0, 0, 0);
  }
}

// Kernel 5a: pass1 — rowsum[row] += sum_n exp(logit).  (|logit| < ~10: safe)
__global__ __launch_bounds__(256) void proj_pass1_kernel(
    const ushort_t* __restrict__ A, const ushort_t* __restrict__ BT,
    const float* __restrict__ bout, float* __restrict__ rowsum)
{
  const int mt = blockIdx.x / 250, nt = blockIdx.x % 250;
  const int wave = threadIdx.x >> 6, lane = threadIdx.x & 63;
  const int wm = wave >> 1, wn = wave & 1;
  const int r = lane & 15, kg = lane >> 4;
  const int m0 = mt * 256 + wm * 128;
  const int n0 = nt * 128 + wn * 64;

  f32x4 acc[8][4];
  gemm_tile(A, BT, acc, m0, n0, r, kg);

  float bv[4];
#pragma unroll
  for (int j = 0; j < 4; ++j) bv[j] = bout[n0 + j * 16 + r];

#pragma unroll
  for (int i = 0; i < 8; ++i)
#pragma unroll
    for (int q = 0; q < 4; ++q) {
      float v = 0.0f;
#pragma unroll
      for (int j = 0; j < 4; ++j) v += __expf(acc[i][j][q] + bv[j]);
#pragma unroll
      for (int msk = 1; msk < 16; msk <<= 1) v += __shfl_xor(v, msk, 64);
      if (r == 0) atomicAdd(&rowsum[m0 + i * 16 + kg * 4 + q], v);
    }
}

// Kernel 5b: pass2 — recompute GEMM, write probs = exp(logit)/rowsum.
__global__ __launch_bounds__(256) void proj_pass2_kernel(
    const ushort_t* __restrict__ A, const ushort_t* __restrict__ BT,
    const float* __restrict__ bout, const float* __restrict__ rowsum,
    float* __restrict__ out)
{
  const int mt = blockIdx.x / 250, nt = blockIdx.x % 250;
  const int wave = threadIdx.x >> 6, lane = threadIdx.x & 63;
  const int wm = wave >> 1, wn = wave & 1;
  const int r = lane & 15, kg = lane >> 4;
  const int m0 = mt * 256 + wm * 128;
  const int n0 = nt * 128 + wn * 64;

  f32x4 acc[8][4];
  gemm_tile(A, BT, acc, m0, n0, r, kg);

  float bv[4];
#pragma unroll
  for (int j = 0; j < 4; ++j) bv[j] = bout[n0 + j * 16 + r];

#pragma unroll
  for (int i = 0; i < 8; ++i)
#pragma unroll
    for (int q = 0; q < 4; ++q) {
      const int row = m0 + i * 16 + kg * 4 + q;
      const float inv = 1.0f / rowsum[row];
#pragma unroll
      for (int j = 0; j < 4; ++j)
        out[(size_t)row * VOCAB + n0 + j * 16 + r] =
            __expf(acc[i][j][q] + bv[j]) * inv;
    }
}

// ---------------------------------------------------------------------------
// Host launcher
// ---------------------------------------------------------------------------
extern "C" void kernel_launch(void* const* d_in, const int* in_sizes, int n_in,
                              void* d_out, int out_size, void* d_ws, size_t ws_size,
                              hipStream_t stream) {
  (void)in_sizes; (void)n_in; (void)out_size; (void)ws_size;

  const int*   x       = (const int*)d_in[0];
  const int*   y       = (const int*)d_in[1];
  const float* enc_emb = (const float*)d_in[2];
  const float* enc_Wk  = (const float*)d_in[3];
  const float* enc_Wr  = (const float*)d_in[4];
  const float* enc_b   = (const float*)d_in[5];
  const float* dec_emb = (const float*)d_in[6];
  const float* dec_Wk  = (const float*)d_in[7];
  const float* dec_Wr  = (const float*)d_in[8];
  const float* dec_b   = (const float*)d_in[9];
  const float* Wout    = (const float*)d_in[10];
  const float* bout    = (const float*)d_in[11];
  float* out = (float*)d_out;
  char*  ws  = (char*)d_ws;

  // workspace layout (bytes)
  size_t off = 0;
  float* xz_enc = (float*)(ws + off); off += (size_t)BB * LS * G4 * 4;      // 16 MB
  float* xz_dec = (float*)(ws + off); off += (size_t)BB * LT * G4 * 4;      //  8 MB
  float* Henc   = (float*)(ws + off); off += (size_t)BB * LS * HID * 4;     //  4 MB
  float* S      = (float*)(ws + off); off += (size_t)BB * LT * HID * 4;     //  2 MB
  __hip_bfloat16* featB = (__hip_bfloat16*)(ws + off);
  off += (size_t)BB * LT * 2 * HID * 2;                                     //  2 MB
  ushort_t* WoutT = (ushort_t*)(ws + off); off += (size_t)VOCAB * 512 * 2;  // 32 MB
  float* c_fin  = (float*)(ws + off); off += (size_t)BB * HID * 4;
  float* rowsum = (float*)(ws + off); off += (size_t)BB * LT * 4;           //  8 KB
  i32x4* mbox_enc = (i32x4*)(ws + off); off += (size_t)BB * LS * 128 * 16;  //  8 MB
  i32x4* mbox_dec = (i32x4*)(ws + off); off += (size_t)BB * LT * 128 * 16;  //  4 MB

  // zero mailboxes (checksum chunks never validate as zero) + rowsums
  hipMemsetAsync(mbox_enc, 0, (size_t)BB * (LS + LT) * 128 * 16, stream);
  hipMemsetAsync(rowsum, 0, (size_t)BB * LT * 4, stream);

  // input projections
  embed_proj_kernel<<<(BB * LS) / 32, 256, 0, stream>>>(x, enc_emb, enc_Wk, enc_b, xz_enc);
  embed_proj_kernel<<<(BB * LT) / 32, 256, 0, stream>>>(y, dec_emb, dec_Wk, dec_b, xz_dec);

  // encoder LSTM (h0=c0=0): 128 WGs
  lstm_kernel<<<NSL * BB, 256, 0, stream>>>(
      xz_enc, enc_Wr, nullptr, 0, nullptr, Henc, c_fin, mbox_enc, LS);

  // decoder LSTM (h0 = enc final h rows inside Henc, c0 = c_fin)
  lstm_kernel<<<NSL * BB, 256, 0, stream>>>(
      xz_dec, dec_Wr, Henc + (size_t)(LS - 1) * HID, LS * HID, c_fin,
      S, nullptr, mbox_dec, LT);

  // attention + bf16 feat pack
  attn_kernel<<<BB * LT, 256, 0, stream>>>(Henc, S, featB);

  // prepack Wout -> transposed bf16
  prepack_wt_kernel<<<8 * 500, 256, 0, stream>>>(Wout, WoutT);

  // vocab projection + softmax, no logits materialization
  proj_pass1_kernel<<<8 * 250, 256, 0, stream>>>(
      (const ushort_t*)featB, WoutT, bout, rowsum);
  proj_pass2_kernel<<<8 * 250, 256, 0, stream>>>(
      (const ushort_t*)featB, WoutT, bout, rowsum, out);
}

// Round 5
// 1733.325 us; speedup vs baseline: 1.1016x; 1.1016x over previous
//
#include <hip/hip_runtime.h>
#include <hip/hip_bf16.h>
#include <math.h>

// Problem constants
#define BB    16
#define LS    256
#define LT    128
#define EMB   128
#define HID   256
#define G4    1024      // 4*HID
#define VOCAB 32000

// LSTM slicing: 8 slice-WGs per batch, each owns 32 hidden units (128 gate cols)
#define NSL   8

typedef __attribute__((ext_vector_type(8))) short bf16x8;
typedef __attribute__((ext_vector_type(4))) float f32x4;
typedef __attribute__((ext_vector_type(4))) int   i32x4;
typedef unsigned short ushort_t;
typedef unsigned int uint_t;

__device__ inline float sigf(float x)      { return 1.0f / (1.0f + __expf(-x)); }
__device__ inline float tanhfast(float x)  { return 1.0f - 2.0f / (1.0f + __expf(2.0f * x)); }
__device__ inline ushort_t bf16_rne(float f) {
  __hip_bfloat16 h = __float2bfloat16(f);
  return *(ushort_t*)&h;
}

// ---------------------------------------------------------------------------
// Kernel 1: xz = emb[idx] @ Wk + b.  32 rows/WG to cut Wk re-reads.
// ---------------------------------------------------------------------------
__global__ __launch_bounds__(256) void embed_proj_kernel(
    const int* __restrict__ idx, const float* __restrict__ emb,
    const float* __restrict__ Wk, const float* __restrict__ bias,
    float* __restrict__ xz)
{
  __shared__ float e[32][EMB];    // 16 KB
  const int row0 = blockIdx.x * 32;
  const int tid = threadIdx.x;

  for (int i = tid; i < 32 * EMB; i += 256) {
    int r = i >> 7, k = i & 127;
    int token = idx[row0 + r];
    e[r][k] = emb[(size_t)token * EMB + k];
  }
  __syncthreads();

  float acc[4][32];
#pragma unroll
  for (int q = 0; q < 4; ++q)
#pragma unroll
    for (int r = 0; r < 32; ++r) acc[q][r] = 0.0f;

  for (int k = 0; k < EMB; ++k) {
    float w0 = Wk[(size_t)k * G4 + 0 * 256 + tid];
    float w1 = Wk[(size_t)k * G4 + 1 * 256 + tid];
    float w2 = Wk[(size_t)k * G4 + 2 * 256 + tid];
    float w3 = Wk[(size_t)k * G4 + 3 * 256 + tid];
#pragma unroll
    for (int r = 0; r < 32; ++r) {
      float ev = e[r][k];
      acc[0][r] = fmaf(ev, w0, acc[0][r]);
      acc[1][r] = fmaf(ev, w1, acc[1][r]);
      acc[2][r] = fmaf(ev, w2, acc[2][r]);
      acc[3][r] = fmaf(ev, w3, acc[3][r]);
    }
  }
#pragma unroll
  for (int q = 0; q < 4; ++q) {
    float bb = bias[q * 256 + tid];
#pragma unroll
    for (int r = 0; r < 32; ++r)
      xz[(size_t)(row0 + r) * G4 + q * 256 + tid] = acc[q][r] + bb;
  }
}

// ---------------------------------------------------------------------------
// Kernel 2: LSTM recurrence, 8 slice-WGs per batch (128 WGs).
// EXACT R3-proven protocol: far-scope (sc0 sc1) checksummed mailbox chunks
// {h0,h1,h0^h1^(t+1),0}. One poll load returns data + validity. Torn reads
// either fail checksum (retry) or are value-correct. Zeroed mailbox never
// validates (stamp t+1 != 0). Separate enc/dec mailboxes.
// ---------------------------------------------------------------------------
__global__ __launch_bounds__(256, 1) void lstm_kernel(
    const float* __restrict__ xz,    // [B*T, 1024]
    const float* __restrict__ Wr,    // [256, 1024]
    const float* __restrict__ h0,    // null => zeros; row stride h0_stride
    int h0_stride,
    const float* __restrict__ cinit, // null => zeros; [B,256]
    float* __restrict__ Hout,        // [B*T, 256]
    float* __restrict__ c_fin,       // [B, 256] or null
    i32x4* __restrict__ mbox,        // [B*T*128] chunks, zeroed at launch
    int T)
{
  const int b    = blockIdx.x & (BB - 1);
  const int s    = blockIdx.x >> 4;
  const int tid  = threadIdx.x;
  const int lane = tid & 63;
  const int half = tid >> 7;           // 0: h[0..127], 1: h[128..255]
  const int col  = tid & 127;          // gate col within slice
  const int gate = col >> 5, u = col & 31;

  __shared__ float part[2][128];

  // weight column slice in registers: w_r[j] = Wr[half*128+j][gate*256+s*32+u]
  float w_r[128];
  {
    const float* wp = Wr + (size_t)(half * 128) * G4 + gate * 256 + s * 32 + u;
#pragma unroll
    for (int j = 0; j < 128; ++j) w_r[j] = wp[(size_t)j * G4];
  }

  // h layout for readlane dot: hv0 = h[half*128+lane], hv1 = h[half*128+64+lane]
  const int i0 = half * 128 + lane;
  float hv0 = 0.0f, hv1 = 0.0f;
  if (h0) {
    hv0 = h0[(size_t)b * h0_stride + i0];
    hv1 = h0[(size_t)b * h0_stride + i0 + 64];
  }
  // cell state: threads 0..15 carry 2 adjacent units each
  float cs0 = 0.0f, cs1 = 0.0f;
  if (tid < 16 && cinit) {
    cs0 = cinit[b * HID + s * 32 + 2 * tid];
    cs1 = cinit[b * HID + s * 32 + 2 * tid + 1];
  }

  const int c0i = i0 >> 1;         // chunk for hv0 (chunk for hv1 = c0i+32)
  const int sel = i0 & 1;

  for (int t = 0; t < T; ++t) {
    // prefetch xz for pointwise (threads 0..15, 2 units each, 4 gates)
    float2 xg0, xg1, xg2, xg3;
    if (tid < 16) {
      const float* xp = xz + ((size_t)b * T + t) * G4 + s * 32 + 2 * tid;
      xg0 = *(const float2*)(xp);
      xg1 = *(const float2*)(xp + 256);
      xg2 = *(const float2*)(xp + 512);
      xg3 = *(const float2*)(xp + 768);
    }

    // partial dot over this half's 128 h values
    float acc = 0.0f;
#pragma unroll
    for (int j = 0; j < 64; ++j) {
      float sa = __int_as_float(__builtin_amdgcn_readlane(__float_as_int(hv0), j));
      acc = fmaf(sa, w_r[j], acc);
    }
#pragma unroll
    for (int j = 0; j < 64; ++j) {
      float sb = __int_as_float(__builtin_amdgcn_readlane(__float_as_int(hv1), j));
      acc = fmaf(sb, w_r[64 + j], acc);
    }
    part[half][col] = acc;
    __syncthreads();

    // pointwise: thread q<16 computes units 2q,2q+1; writes Hout + mailbox
    if (tid < 16) {
      const int ua = 2 * tid, ub = ua + 1;
      float zi0 = part[0][ua]      + part[1][ua]      + xg0.x;
      float zi1 = part[0][ub]      + part[1][ub]      + xg0.y;
      float zf0 = part[0][32 + ua] + part[1][32 + ua] + xg1.x;
      float zf1 = part[0][32 + ub] + part[1][32 + ub] + xg1.y;
      float zg0 = part[0][64 + ua] + part[1][64 + ua] + xg2.x;
      float zg1 = part[0][64 + ub] + part[1][64 + ub] + xg2.y;
      float zo0 = part[0][96 + ua] + part[1][96 + ua] + xg3.x;
      float zo1 = part[0][96 + ub] + part[1][96 + ub] + xg3.y;

      cs0 = fmaf(sigf(zf0), cs0, sigf(zi0) * tanhfast(zg0));
      cs1 = fmaf(sigf(zf1), cs1, sigf(zi1) * tanhfast(zg1));
      float ha = sigf(zo0) * tanhfast(cs0);
      float hb = sigf(zo1) * tanhfast(cs1);

      *(float2*)&Hout[((size_t)b * T + t) * HID + s * 32 + ua] = make_float2(ha, hb);

      i32x4 ch;
      ch.x = __float_as_int(ha);
      ch.y = __float_as_int(hb);
      ch.z = ch.x ^ ch.y ^ (t + 1);
      ch.w = 0;
      const i32x4* dst = mbox + ((size_t)b * T + t) * 128 + (s * 16 + tid);
      asm volatile("global_store_dwordx4 %0, %1, off sc0 sc1"
                   :: "v"(dst), "v"(ch) : "memory");
    }

    // poll next h: each thread needs chunks c0i and c0i+32 of slot t
    if (t + 1 < T) {
      const i32x4* pa = mbox + ((size_t)b * T + t) * 128 + c0i;
      const i32x4* pb = pa + 32;
      const int stamp = t + 1;
      i32x4 va, vb;
      for (;;) {
        asm volatile(
            "global_load_dwordx4 %0, %2, off sc0 sc1\n\t"
            "global_load_dwordx4 %1, %3, off sc0 sc1\n\t"
            "s_waitcnt vmcnt(0)"
            : "=&v"(va), "=&v"(vb)
            : "v"(pa), "v"(pb)
            : "memory");
        if ((va.z == (va.x ^ va.y ^ stamp)) && (vb.z == (vb.x ^ vb.y ^ stamp)))
          break;
      }
      hv0 = __int_as_float(sel ? va.y : va.x);
      hv1 = __int_as_float(sel ? vb.y : vb.x);
    }
  }
  if (c_fin && tid < 16)
    *(float2*)&c_fin[b * HID + s * 32 + 2 * tid] = make_float2(cs0, cs1);
}

// ---------------------------------------------------------------------------
// Kernel 3: attention + feat pack -> featB (bf16 [M=2048][K=512]).
// ---------------------------------------------------------------------------
__global__ __launch_bounds__(256) void attn_kernel(
    const float* __restrict__ Henc, const float* __restrict__ S,
    __hip_bfloat16* __restrict__ featB)
{
  const int m = blockIdx.x;          // b*LT + t
  const int b = m >> 7, t = m & (LT - 1);
  const int tid = threadIdx.x;

  __shared__ float srow[HID];
  __shared__ float p[LS];
  __shared__ float sm[LS];

  const float* s_ = (t == 0) ? (Henc + ((size_t)b * LS + (LS - 1)) * HID)
                             : (S + (size_t)(m - 1) * HID);
  srow[tid] = s_[tid];
  __syncthreads();

  const float4* h4 = (const float4*)(Henc + ((size_t)b * LS + tid) * HID);
  const float4* s4 = (const float4*)srow;
  float sc = 0.0f;
#pragma unroll 8
  for (int k = 0; k < HID / 4; ++k) {
    float4 a = h4[k], q = s4[k];
    sc += a.x * q.x + a.y * q.y + a.z * q.z + a.w * q.w;
  }
  sm[tid] = sc;
  __syncthreads();
  for (int st = 128; st > 0; st >>= 1) {
    if (tid < st) sm[tid] = fmaxf(sm[tid], sm[tid + st]);
    __syncthreads();
  }
  float mx = sm[0];
  __syncthreads();
  float e = __expf(sc - mx);
  p[tid] = e;
  sm[tid] = e;
  __syncthreads();
  for (int st = 128; st > 0; st >>= 1) {
    if (tid < st) sm[tid] += sm[tid + st];
    __syncthreads();
  }
  float inv = 1.0f / sm[0];

  float a_d = 0.0f;
#pragma unroll 4
  for (int s2 = 0; s2 < LS; ++s2)
    a_d = fmaf(p[s2], Henc[((size_t)b * LS + s2) * HID + tid], a_d);
  a_d *= inv;

  featB[(size_t)m * (2 * HID) + tid]       = __float2bfloat16(S[(size_t)m * HID + tid]);
  featB[(size_t)m * (2 * HID) + HID + tid] = __float2bfloat16(a_d);
}

// ---------------------------------------------------------------------------
// Kernel 4: prepack WoutT[n][k] = bf16(Wout[k][n]). 64x64 tiles via LDS.
// ---------------------------------------------------------------------------
__global__ __launch_bounds__(256) void prepack_wt_kernel(
    const float* __restrict__ W, ushort_t* __restrict__ WT)
{
  __shared__ float tile[64][65];
  const int nt = blockIdx.x % 500;
  const int kt = blockIdx.x / 500;
  const int n0 = nt * 64, k0 = kt * 64;
  const int tid = threadIdx.x;
  const int r = tid >> 6, c = tid & 63;

#pragma unroll
  for (int q = 0; q < 16; ++q) {
    int kk = q * 4 + r;
    tile[kk][c] = W[(size_t)(k0 + kk) * VOCAB + n0 + c];
  }
  __syncthreads();

  const int nl = tid >> 2;             // 0..63 output row
  const int seg = (tid & 3) * 16;      // 16 k per thread
  uint_t o[8];
#pragma unroll
  for (int j = 0; j < 8; ++j) {
    uint_t lo = bf16_rne(tile[seg + 2 * j][nl]);
    uint_t hi = bf16_rne(tile[seg + 2 * j + 1][nl]);
    o[j] = lo | (hi << 16);
  }
  ushort_t* dst = WT + (size_t)(n0 + nl) * 512 + k0 + seg;
  ((uint4*)dst)[0] = make_uint4(o[0], o[1], o[2], o[3]);
  ((uint4*)dst)[1] = make_uint4(o[4], o[5], o[6], o[7]);
}

// ---------------------------------------------------------------------------
// GEMM core: 256x128 tile, 4 waves (2x2), wave tile 128x64, direct loads.
// ---------------------------------------------------------------------------
__device__ inline void gemm_tile(
    const ushort_t* __restrict__ A, const ushort_t* __restrict__ BT,
    f32x4 (&acc)[8][4], int m0, int n0, int r, int kg)
{
#pragma unroll
  for (int i = 0; i < 8; ++i)
#pragma unroll
    for (int j = 0; j < 4; ++j) acc[i][j] = (f32x4){0.f, 0.f, 0.f, 0.f};

  for (int ks = 0; ks < 16; ++ks) {
    const int kb = ks * 32 + kg * 8;
    bf16x8 a[8], bb[4];
#pragma unroll
    for (int i = 0; i < 8; ++i)
      a[i] = *(const bf16x8*)(A + (size_t)(m0 + i * 16 + r) * 512 + kb);
#pragma unroll
    for (int j = 0; j < 4; ++j)
      bb[j] = *(const bf16x8*)(BT + (size_t)(n0 + j * 16 + r) * 512 + kb);
#pragma unroll
    for (int i = 0; i < 8; ++i)
#pragma unroll
      for (int j = 0; j < 4; ++j)
        acc[i][j] = __builtin_amdgcn_mfma_f32_16x16x32_bf16(a[i], bb[j], acc[i][j], 0, 0, 0);
  }
}

// Kernel 5: GEMM -> E = exp(logit) written unnormalized + rowsum atomics.
// |logit| < ~10 by construction (|feat|<=1, Wout ~ N(0,1/sqrt(512))): exp safe.
__global__ __launch_bounds__(256) void proj_exp_kernel(
    const ushort_t* __restrict__ A, const ushort_t* __restrict__ BT,
    const float* __restrict__ bout, float* __restrict__ rowsum,
    float* __restrict__ out)
{
  const int mt = blockIdx.x / 250, nt = blockIdx.x % 250;
  const int wave = threadIdx.x >> 6, lane = threadIdx.x & 63;
  const int wm = wave >> 1, wn = wave & 1;
  const int r = lane & 15, kg = lane >> 4;
  const int m0 = mt * 256 + wm * 128;
  const int n0 = nt * 128 + wn * 64;

  f32x4 acc[8][4];
  gemm_tile(A, BT, acc, m0, n0, r, kg);

  float bv[4];
#pragma unroll
  for (int j = 0; j < 4; ++j) bv[j] = bout[n0 + j * 16 + r];

#pragma unroll
  for (int i = 0; i < 8; ++i)
#pragma unroll
    for (int q = 0; q < 4; ++q) {
      const int row = m0 + i * 16 + kg * 4 + q;
      float v = 0.0f;
#pragma unroll
      for (int j = 0; j < 4; ++j) {
        float e = __expf(acc[i][j][q] + bv[j]);
        out[(size_t)row * VOCAB + n0 + j * 16 + r] = e;
        v += e;
      }
#pragma unroll
      for (int msk = 1; msk < 16; msk <<= 1) v += __shfl_xor(v, msk, 64);
      if (r == 0) atomicAdd(&rowsum[row], v);
    }
}

// Kernel 6: rowsum -> 1/rowsum (tiny)
__global__ __launch_bounds__(256) void invert_kernel(float* __restrict__ r)
{
  int i = blockIdx.x * 256 + threadIdx.x;
  if (i < BB * LT) r[i] = 1.0f / r[i];
}

// Kernel 7: out *= inv[row]  (pure stream, float4). 4 blocks per row.
__global__ __launch_bounds__(256) void scale_kernel(
    float* __restrict__ out, const float* __restrict__ inv)
{
  const int row = blockIdx.x >> 2;       // 0..2047
  const int seg = blockIdx.x & 3;        // 4 segments of 2000 float4
  const float s = inv[row];
  float4* o4 = (float4*)(out + (size_t)row * VOCAB) + seg * 2000;
  for (int i = threadIdx.x; i < 2000; i += 256) {
    float4 v = o4[i];
    v.x *= s; v.y *= s; v.z *= s; v.w *= s;
    o4[i] = v;
  }
}

// ---------------------------------------------------------------------------
// Host launcher
// ---------------------------------------------------------------------------
extern "C" void kernel_launch(void* const* d_in, const int* in_sizes, int n_in,
                              void* d_out, int out_size, void* d_ws, size_t ws_size,
                              hipStream_t stream) {
  (void)in_sizes; (void)n_in; (void)out_size; (void)ws_size;

  const int*   x       = (const int*)d_in[0];
  const int*   y       = (const int*)d_in[1];
  const float* enc_emb = (const float*)d_in[2];
  const float* enc_Wk  = (const float*)d_in[3];
  const float* enc_Wr  = (const float*)d_in[4];
  const float* enc_b   = (const float*)d_in[5];
  const float* dec_emb = (const float*)d_in[6];
  const float* dec_Wk  = (const float*)d_in[7];
  const float* dec_Wr  = (const float*)d_in[8];
  const float* dec_b   = (const float*)d_in[9];
  const float* Wout    = (const float*)d_in[10];
  const float* bout    = (const float*)d_in[11];
  float* out = (float*)d_out;
  char*  ws  = (char*)d_ws;

  // workspace layout (bytes) — identical footprint to the R3-proven run
  size_t off = 0;
  float* xz_enc = (float*)(ws + off); off += (size_t)BB * LS * G4 * 4;      // 16 MB
  float* xz_dec = (float*)(ws + off); off += (size_t)BB * LT * G4 * 4;      //  8 MB
  float* Henc   = (float*)(ws + off); off += (size_t)BB * LS * HID * 4;     //  4 MB
  float* S      = (float*)(ws + off); off += (size_t)BB * LT * HID * 4;     //  2 MB
  __hip_bfloat16* featB = (__hip_bfloat16*)(ws + off);
  off += (size_t)BB * LT * 2 * HID * 2;                                     //  2 MB
  ushort_t* WoutT = (ushort_t*)(ws + off); off += (size_t)VOCAB * 512 * 2;  // 32 MB
  float* c_fin  = (float*)(ws + off); off += (size_t)BB * HID * 4;
  float* rowsum = (float*)(ws + off); off += (size_t)BB * LT * 4;           //  8 KB
  i32x4* mbox_enc = (i32x4*)(ws + off); off += (size_t)BB * LS * 128 * 16;  //  8 MB
  i32x4* mbox_dec = (i32x4*)(ws + off); off += (size_t)BB * LT * 128 * 16;  //  4 MB

  // zero mailboxes (checksum chunks never validate as zero) + rowsums
  hipMemsetAsync(mbox_enc, 0, (size_t)BB * (LS + LT) * 128 * 16, stream);
  hipMemsetAsync(rowsum, 0, (size_t)BB * LT * 4, stream);

  // input projections
  embed_proj_kernel<<<(BB * LS) / 32, 256, 0, stream>>>(x, enc_emb, enc_Wk, enc_b, xz_enc);
  embed_proj_kernel<<<(BB * LT) / 32, 256, 0, stream>>>(y, dec_emb, dec_Wk, dec_b, xz_dec);

  // encoder LSTM (h0=c0=0): 128 WGs
  lstm_kernel<<<NSL * BB, 256, 0, stream>>>(
      xz_enc, enc_Wr, nullptr, 0, nullptr, Henc, c_fin, mbox_enc, LS);

  // decoder LSTM (h0 = enc final h rows inside Henc, c0 = c_fin)
  lstm_kernel<<<NSL * BB, 256, 0, stream>>>(
      xz_dec, dec_Wr, Henc + (size_t)(LS - 1) * HID, LS * HID, c_fin,
      S, nullptr, mbox_dec, LT);

  // attention + bf16 feat pack
  attn_kernel<<<BB * LT, 256, 0, stream>>>(Henc, S, featB);

  // prepack Wout -> transposed bf16
  prepack_wt_kernel<<<8 * 500, 256, 0, stream>>>(Wout, WoutT);

  // GEMM + exp (unnormalized) + rowsum; then invert; then scale
  proj_exp_kernel<<<8 * 250, 256, 0, stream>>>(
      (const ushort_t*)featB, WoutT, bout, rowsum, out);
  invert_kernel<<<8, 256, 0, stream>>>(rowsum);
  scale_kernel<<<4 * BB * LT, 256, 0, stream>>>(out, rowsum);
}

// Round 6
// 1391.183 us; speedup vs baseline: 1.3725x; 1.2459x over previous
//
#include <hip/hip_runtime.h>
#include <hip/hip_bf16.h>
#include <math.h>

// Problem constants
#define BB    16
#define LS    256
#define LT    128
#define EMB   128
#define HID   256
#define G4    1024      // 4*HID
#define VOCAB 32000

// LSTM slicing: 8 slice-WGs per batch, 512 threads each.
// Thread (quarter, col): quarter = tid>>7 covers 64 of the 256 h-dims,
// col = tid&127 is the gate column (gate = col>>5, u = col&31).
#define NSL   8
#define XROWS 112      // LDS-staged xz steps per burst (56 KB)

typedef __attribute__((ext_vector_type(8))) short bf16x8;
typedef __attribute__((ext_vector_type(4))) float f32x4;
typedef __attribute__((ext_vector_type(4))) int   i32x4;
typedef unsigned short ushort_t;
typedef unsigned int uint_t;

__device__ inline float sigf(float x)      { return 1.0f / (1.0f + __expf(-x)); }
__device__ inline float tanhfast(float x)  { return 1.0f - 2.0f / (1.0f + __expf(2.0f * x)); }
__device__ inline ushort_t bf16_rne(float f) {
  __hip_bfloat16 h = __float2bfloat16(f);
  return *(ushort_t*)&h;
}

// ---------------------------------------------------------------------------
// Kernel 1: xz = emb[idx] @ Wk + b.  32 rows/WG to cut Wk re-reads.
// ---------------------------------------------------------------------------
__global__ __launch_bounds__(256) void embed_proj_kernel(
    const int* __restrict__ idx, const float* __restrict__ emb,
    const float* __restrict__ Wk, const float* __restrict__ bias,
    float* __restrict__ xz)
{
  __shared__ float e[32][EMB];    // 16 KB
  const int row0 = blockIdx.x * 32;
  const int tid = threadIdx.x;

  for (int i = tid; i < 32 * EMB; i += 256) {
    int r = i >> 7, k = i & 127;
    int token = idx[row0 + r];
    e[r][k] = emb[(size_t)token * EMB + k];
  }
  __syncthreads();

  float acc[4][32];
#pragma unroll
  for (int q = 0; q < 4; ++q)
#pragma unroll
    for (int r = 0; r < 32; ++r) acc[q][r] = 0.0f;

  for (int k = 0; k < EMB; ++k) {
    float w0 = Wk[(size_t)k * G4 + 0 * 256 + tid];
    float w1 = Wk[(size_t)k * G4 + 1 * 256 + tid];
    float w2 = Wk[(size_t)k * G4 + 2 * 256 + tid];
    float w3 = Wk[(size_t)k * G4 + 3 * 256 + tid];
#pragma unroll
    for (int r = 0; r < 32; ++r) {
      float ev = e[r][k];
      acc[0][r] = fmaf(ev, w0, acc[0][r]);
      acc[1][r] = fmaf(ev, w1, acc[1][r]);
      acc[2][r] = fmaf(ev, w2, acc[2][r]);
      acc[3][r] = fmaf(ev, w3, acc[3][r]);
    }
  }
#pragma unroll
  for (int q = 0; q < 4; ++q) {
    float bb = bias[q * 256 + tid];
#pragma unroll
    for (int r = 0; r < 32; ++r)
      xz[(size_t)(row0 + r) * G4 + q * 256 + tid] = acc[q][r] + bb;
  }
}

// ---------------------------------------------------------------------------
// Kernel 2: LSTM recurrence, 8 slice-WGs per batch (128 WGs x 512 threads).
// Fail-open dual mailbox: producers store each checksummed chunk
// {h0,h1,h0^h1^stamp,0} (stamp = (t+1)|(kid<<20)) to BOTH the near buffer
// (sc0 only: local-XCD L2, fast when slices co-located) and the far buffer
// (sc0 sc1: LLC, the R3/R5-proven path). Consumers alternate near/far polls
// each iteration — forward progress NEVER depends on the near path.
// Any checksum-valid chunk is correct: position encodes (b, t-parity, chunk),
// stamp encodes (t, kid), h is deterministic across launches/replays.
// Mailboxes are slot-parity (t&1): a WG can only write slot parity t after
// every WG passed the poll of t-2 (production lattice), so reuse is safe.
// xz is LDS-staged in 112-step bursts to keep HBM latency off the step path.
// ---------------------------------------------------------------------------
__global__ __launch_bounds__(512, 1) void lstm_kernel(
    const float* __restrict__ xz,    // [B*T, 1024]
    const float* __restrict__ Wr,    // [256, 1024]
    const float* __restrict__ h0,    // null => zeros; row stride h0_stride
    int h0_stride,
    const float* __restrict__ cinit, // null => zeros; [B,256]
    float* __restrict__ Hout,        // [B*T, 256]
    float* __restrict__ c_fin,       // [B, 256] or null
    i32x4* __restrict__ nmb,         // near mailbox [B*2*128], zeroed
    i32x4* __restrict__ fmb,         // far  mailbox [B*2*128], zeroed
    int kid,                         // 0=enc, 1=dec (stamp tag)
    int T)
{
  const int b    = blockIdx.x & (BB - 1);
  const int s    = blockIdx.x >> 4;
  const int tid  = threadIdx.x;
  const int lane = tid & 63;
  const int quarter = tid >> 7;        // 0..3 : h-dim range quarter*64..+64
  const int col  = tid & 127;          // gate col within slice
  const int gate = col >> 5, u = col & 31;

  __shared__ float part[4][128];       // 2 KB
  __shared__ float xbuf[XROWS][128];   // 56 KB staged xz rows

  // weight column slice in registers: w_r[j] = Wr[quarter*64+j][gate*256+s*32+u]
  float w_r[64];
  {
    const float* wp = Wr + (size_t)(quarter * 64) * G4 + gate * 256 + s * 32 + u;
#pragma unroll
    for (int j = 0; j < 64; ++j) w_r[j] = wp[(size_t)j * G4];
  }

  // this thread holds h[i0]; both waves of a quarter replicate the same 64 h
  const int i0 = quarter * 64 + lane;
  float hv = 0.0f;
  if (h0) hv = h0[(size_t)b * h0_stride + i0];

  // cell state: threads 0..15 carry 2 adjacent units each
  float cs0 = 0.0f, cs1 = 0.0f;
  if (tid < 16 && cinit) {
    cs0 = cinit[b * HID + s * 32 + 2 * tid];
    cs1 = cinit[b * HID + s * 32 + 2 * tid + 1];
  }

  const int c0i = i0 >> 1;   // mailbox chunk holding h[i0]
  const int sel = i0 & 1;

  int tp = XROWS;
  for (int t = 0; t < T; ++t, ++tp) {
    // ---- periodic xz burst into LDS ----
    if (tp >= XROWS) {
      tp = 0;
      for (int tt = quarter; tt < XROWS; tt += 4) {
        int ts = t + tt;
        if (ts < T)
          xbuf[tt][col] = xz[((size_t)b * T + ts) * G4 + gate * 256 + s * 32 + u];
      }
    }

    // ---- partial dot over this quarter's 64 h values (4 chains) ----
    float a0 = 0.0f, a1 = 0.0f, a2 = 0.0f, a3 = 0.0f;
#pragma unroll
    for (int j = 0; j < 64; j += 4) {
      a0 = fmaf(__int_as_float(__builtin_amdgcn_readlane(__float_as_int(hv), j + 0)), w_r[j + 0], a0);
      a1 = fmaf(__int_as_float(__builtin_amdgcn_readlane(__float_as_int(hv), j + 1)), w_r[j + 1], a1);
      a2 = fmaf(__int_as_float(__builtin_amdgcn_readlane(__float_as_int(hv), j + 2)), w_r[j + 2], a2);
      a3 = fmaf(__int_as_float(__builtin_amdgcn_readlane(__float_as_int(hv), j + 3)), w_r[j + 3], a3);
    }
    part[quarter][col] = (a0 + a1) + (a2 + a3);
    __syncthreads();

    const int stamp = (t + 1) | (kid << 20);
    const size_t slot = (size_t)(b * 2 + (t & 1)) * 128;

    // ---- pointwise: thread q<16 computes units 2q,2q+1; publish chunk ----
    if (tid < 16) {
      const int ua = 2 * tid, ub = ua + 1;
      float p0a = part[0][ua] + part[1][ua] + part[2][ua] + part[3][ua];
      float p0b = part[0][ub] + part[1][ub] + part[2][ub] + part[3][ub];
      float p1a = part[0][32 + ua] + part[1][32 + ua] + part[2][32 + ua] + part[3][32 + ua];
      float p1b = part[0][32 + ub] + part[1][32 + ub] + part[2][32 + ub] + part[3][32 + ub];
      float p2a = part[0][64 + ua] + part[1][64 + ua] + part[2][64 + ua] + part[3][64 + ua];
      float p2b = part[0][64 + ub] + part[1][64 + ub] + part[2][64 + ub] + part[3][64 + ub];
      float p3a = part[0][96 + ua] + part[1][96 + ua] + part[2][96 + ua] + part[3][96 + ua];
      float p3b = part[0][96 + ub] + part[1][96 + ub] + part[2][96 + ub] + part[3][96 + ub];
      float2 xg0 = *(const float2*)&xbuf[tp][ua];
      float2 xg1 = *(const float2*)&xbuf[tp][32 + ua];
      float2 xg2 = *(const float2*)&xbuf[tp][64 + ua];
      float2 xg3 = *(const float2*)&xbuf[tp][96 + ua];

      float zi0 = p0a + xg0.x, zi1 = p0b + xg0.y;
      float zf0 = p1a + xg1.x, zf1 = p1b + xg1.y;
      float zg0 = p2a + xg2.x, zg1 = p2b + xg2.y;
      float zo0 = p3a + xg3.x, zo1 = p3b + xg3.y;

      cs0 = fmaf(sigf(zf0), cs0, sigf(zi0) * tanhfast(zg0));
      cs1 = fmaf(sigf(zf1), cs1, sigf(zi1) * tanhfast(zg1));
      float ha = sigf(zo0) * tanhfast(cs0);
      float hb = sigf(zo1) * tanhfast(cs1);

      *(float2*)&Hout[((size_t)b * T + t) * HID + s * 32 + ua] = make_float2(ha, hb);

      i32x4 ch;
      ch.x = __float_as_int(ha);
      ch.y = __float_as_int(hb);
      ch.z = ch.x ^ ch.y ^ stamp;
      ch.w = 0;
      const i32x4* nd = nmb + slot + s * 16 + tid;
      const i32x4* fd = fmb + slot + s * 16 + tid;
      asm volatile("global_store_dwordx4 %0, %1, off sc0"
                   :: "v"(nd), "v"(ch) : "memory");
      asm volatile("global_store_dwordx4 %0, %1, off sc0 sc1"
                   :: "v"(fd), "v"(ch) : "memory");
    }
    __syncthreads();   // pointwise reads of part/xbuf done before next writes

    // ---- poll h(t): near (L2) attempt, then far (LLC) attempt, repeat ----
    if (t + 1 < T) {
      const i32x4* np = nmb + slot + c0i;
      const i32x4* fp = fmb + slot + c0i;
      i32x4 v;
      for (;;) {
        asm volatile("global_load_dwordx4 %0, %1, off sc0\n\t"
                     "s_waitcnt vmcnt(0)"
                     : "=&v"(v) : "v"(np) : "memory");
        if (v.z == (v.x ^ v.y ^ stamp)) break;
        asm volatile("global_load_dwordx4 %0, %1, off sc0 sc1\n\t"
                     "s_waitcnt vmcnt(0)"
                     : "=&v"(v) : "v"(fp) : "memory");
        if (v.z == (v.x ^ v.y ^ stamp)) break;
      }
      hv = __int_as_float(sel ? v.y : v.x);
    }
  }
  if (c_fin && tid < 16)
    *(float2*)&c_fin[b * HID + s * 32 + 2 * tid] = make_float2(cs0, cs1);
}

// ---------------------------------------------------------------------------
// Kernel 3: attention + feat pack -> featB (bf16 [M=2048][K=512]).
// ---------------------------------------------------------------------------
__global__ __launch_bounds__(256) void attn_kernel(
    const float* __restrict__ Henc, const float* __restrict__ S,
    __hip_bfloat16* __restrict__ featB)
{
  const int m = blockIdx.x;          // b*LT + t
  const int b = m >> 7, t = m & (LT - 1);
  const int tid = threadIdx.x;

  __shared__ float srow[HID];
  __shared__ float p[LS];
  __shared__ float sm[LS];

  const float* s_ = (t == 0) ? (Henc + ((size_t)b * LS + (LS - 1)) * HID)
                             : (S + (size_t)(m - 1) * HID);
  srow[tid] = s_[tid];
  __syncthreads();

  const float4* h4 = (const float4*)(Henc + ((size_t)b * LS + tid) * HID);
  const float4* s4 = (const float4*)srow;
  float sc = 0.0f;
#pragma unroll 8
  for (int k = 0; k < HID / 4; ++k) {
    float4 a = h4[k], q = s4[k];
    sc += a.x * q.x + a.y * q.y + a.z * q.z + a.w * q.w;
  }
  sm[tid] = sc;
  __syncthreads();
  for (int st = 128; st > 0; st >>= 1) {
    if (tid < st) sm[tid] = fmaxf(sm[tid], sm[tid + st]);
    __syncthreads();
  }
  float mx = sm[0];
  __syncthreads();
  float e = __expf(sc - mx);
  p[tid] = e;
  sm[tid] = e;
  __syncthreads();
  for (int st = 128; st > 0; st >>= 1) {
    if (tid < st) sm[tid] += sm[tid + st];
    __syncthreads();
  }
  float inv = 1.0f / sm[0];

  float a_d = 0.0f;
#pragma unroll 4
  for (int s2 = 0; s2 < LS; ++s2)
    a_d = fmaf(p[s2], Henc[((size_t)b * LS + s2) * HID + tid], a_d);
  a_d *= inv;

  featB[(size_t)m * (2 * HID) + tid]       = __float2bfloat16(S[(size_t)m * HID + tid]);
  featB[(size_t)m * (2 * HID) + HID + tid] = __float2bfloat16(a_d);
}

// ---------------------------------------------------------------------------
// Kernel 4: prepack WoutT[n][k] = bf16(Wout[k][n]). 64x64 tiles via LDS.
// ---------------------------------------------------------------------------
__global__ __launch_bounds__(256) void prepack_wt_kernel(
    const float* __restrict__ W, ushort_t* __restrict__ WT)
{
  __shared__ float tile[64][65];
  const int nt = blockIdx.x % 500;
  const int kt = blockIdx.x / 500;
  const int n0 = nt * 64, k0 = kt * 64;
  const int tid = threadIdx.x;
  const int r = tid >> 6, c = tid & 63;

#pragma unroll
  for (int q = 0; q < 16; ++q) {
    int kk = q * 4 + r;
    tile[kk][c] = W[(size_t)(k0 + kk) * VOCAB + n0 + c];
  }
  __syncthreads();

  const int nl = tid >> 2;             // 0..63 output row
  const int seg = (tid & 3) * 16;      // 16 k per thread
  uint_t o[8];
#pragma unroll
  for (int j = 0; j < 8; ++j) {
    uint_t lo = bf16_rne(tile[seg + 2 * j][nl]);
    uint_t hi = bf16_rne(tile[seg + 2 * j + 1][nl]);
    o[j] = lo | (hi << 16);
  }
  ushort_t* dst = WT + (size_t)(n0 + nl) * 512 + k0 + seg;
  ((uint4*)dst)[0] = make_uint4(o[0], o[1], o[2], o[3]);
  ((uint4*)dst)[1] = make_uint4(o[4], o[5], o[6], o[7]);
}

// ---------------------------------------------------------------------------
// GEMM core: 256x128 tile, 4 waves (2x2), wave tile 128x64, direct loads.
// ---------------------------------------------------------------------------
__device__ inline void gemm_tile(
    const ushort_t* __restrict__ A, const ushort_t* __restrict__ BT,
    f32x4 (&acc)[8][4], int m0, int n0, int r, int kg)
{
#pragma unroll
  for (int i = 0; i < 8; ++i)
#pragma unroll
    for (int j = 0; j < 4; ++j) acc[i][j] = (f32x4){0.f, 0.f, 0.f, 0.f};

  for (int ks = 0; ks < 16; ++ks) {
    const int kb = ks * 32 + kg * 8;
    bf16x8 a[8], bb[4];
#pragma unroll
    for (int i = 0; i < 8; ++i)
      a[i] = *(const bf16x8*)(A + (size_t)(m0 + i * 16 + r) * 512 + kb);
#pragma unroll
    for (int j = 0; j < 4; ++j)
      bb[j] = *(const bf16x8*)(BT + (size_t)(n0 + j * 16 + r) * 512 + kb);
#pragma unroll
    for (int i = 0; i < 8; ++i)
#pragma unroll
      for (int j = 0; j < 4; ++j)
        acc[i][j] = __builtin_amdgcn_mfma_f32_16x16x32_bf16(a[i], bb[j], acc[i][j], 0, 0, 0);
  }
}

// Kernel 5: GEMM -> E = exp(logit) written unnormalized + rowsum atomics.
// |logit| < ~10 by construction: exp safe. XCD-chunked swizzle: each XCD
// owns a contiguous nt-range so B panels are reused within one XCD's L2.
__global__ __launch_bounds__(256) void proj_exp_kernel(
    const ushort_t* __restrict__ A, const ushort_t* __restrict__ BT,
    const float* __restrict__ bout, float* __restrict__ rowsum,
    float* __restrict__ out)
{
  const int k2 = (blockIdx.x & 7) * 250 + (blockIdx.x >> 3);  // XCD-chunked
  const int nt = k2 >> 3;     // 0..249
  const int mt = k2 & 7;      // 0..7
  const int wave = threadIdx.x >> 6, lane = threadIdx.x & 63;
  const int wm = wave >> 1, wn = wave & 1;
  const int r = lane & 15, kg = lane >> 4;
  const int m0 = mt * 256 + wm * 128;
  const int n0 = nt * 128 + wn * 64;

  f32x4 acc[8][4];
  gemm_tile(A, BT, acc, m0, n0, r, kg);

  float bv[4];
#pragma unroll
  for (int j = 0; j < 4; ++j) bv[j] = bout[n0 + j * 16 + r];

#pragma unroll
  for (int i = 0; i < 8; ++i)
#pragma unroll
    for (int q = 0; q < 4; ++q) {
      const int row = m0 + i * 16 + kg * 4 + q;
      float v = 0.0f;
#pragma unroll
      for (int j = 0; j < 4; ++j) {
        float e = __expf(acc[i][j][q] + bv[j]);
        out[(size_t)row * VOCAB + n0 + j * 16 + r] = e;
        v += e;
      }
#pragma unroll
      for (int msk = 1; msk < 16; msk <<= 1) v += __shfl_xor(v, msk, 64);
      if (r == 0) atomicAdd(&rowsum[row], v);
    }
}

// Kernel 6: rowsum -> 1/rowsum (tiny)
__global__ __launch_bounds__(256) void invert_kernel(float* __restrict__ r)
{
  int i = blockIdx.x * 256 + threadIdx.x;
  if (i < BB * LT) r[i] = 1.0f / r[i];
}

// Kernel 7: out *= inv[row]  (pure stream, float4). 4 blocks per row.
__global__ __launch_bounds__(256) void scale_kernel(
    float* __restrict__ out, const float* __restrict__ inv)
{
  const int row = blockIdx.x >> 2;       // 0..2047
  const int seg = blockIdx.x & 3;        // 4 segments of 2000 float4
  const float s = inv[row];
  float4* o4 = (float4*)(out + (size_t)row * VOCAB) + seg * 2000;
  for (int i = threadIdx.x; i < 2000; i += 256) {
    float4 v = o4[i];
    v.x *= s; v.y *= s; v.z *= s; v.w *= s;
    o4[i] = v;
  }
}

// ---------------------------------------------------------------------------
// Host launcher
// ---------------------------------------------------------------------------
extern "C" void kernel_launch(void* const* d_in, const int* in_sizes, int n_in,
                              void* d_out, int out_size, void* d_ws, size_t ws_size,
                              hipStream_t stream) {
  (void)in_sizes; (void)n_in; (void)out_size; (void)ws_size;

  const int*   x       = (const int*)d_in[0];
  const int*   y       = (const int*)d_in[1];
  const float* enc_emb = (const float*)d_in[2];
  const float* enc_Wk  = (const float*)d_in[3];
  const float* enc_Wr  = (const float*)d_in[4];
  const float* enc_b   = (const float*)d_in[5];
  const float* dec_emb = (const float*)d_in[6];
  const float* dec_Wk  = (const float*)d_in[7];
  const float* dec_Wr  = (const float*)d_in[8];
  const float* dec_b   = (const float*)d_in[9];
  const float* Wout    = (const float*)d_in[10];
  const float* bout    = (const float*)d_in[11];
  float* out = (float*)d_out;
  char*  ws  = (char*)d_ws;

  // workspace layout (bytes)
  size_t off = 0;
  float* xz_enc = (float*)(ws + off); off += (size_t)BB * LS * G4 * 4;      // 16 MB
  float* xz_dec = (float*)(ws + off); off += (size_t)BB * LT * G4 * 4;      //  8 MB
  float* Henc   = (float*)(ws + off); off += (size_t)BB * LS * HID * 4;     //  4 MB
  float* S      = (float*)(ws + off); off += (size_t)BB * LT * HID * 4;     //  2 MB
  __hip_bfloat16* featB = (__hip_bfloat16*)(ws + off);
  off += (size_t)BB * LT * 2 * HID * 2;                                     //  2 MB
  ushort_t* WoutT = (ushort_t*)(ws + off); off += (size_t)VOCAB * 512 * 2;  // 32 MB
  float* c_fin  = (float*)(ws + off); off += (size_t)BB * HID * 4;
  float* rowsum = (float*)(ws + off); off += (size_t)BB * LT * 4;           //  8 KB
  i32x4* nmb    = (i32x4*)(ws + off); off += (size_t)BB * 2 * 128 * 16;     // 64 KB
  i32x4* fmb    = (i32x4*)(ws + off); off += (size_t)BB * 2 * 128 * 16;     // 64 KB

  // zero mailboxes (checksum chunks never validate as zero) + rowsums
  hipMemsetAsync(nmb, 0, (size_t)2 * BB * 2 * 128 * 16, stream);
  hipMemsetAsync(rowsum, 0, (size_t)BB * LT * 4, stream);

  // input projections
  embed_proj_kernel<<<(BB * LS) / 32, 256, 0, stream>>>(x, enc_emb, enc_Wk, enc_b, xz_enc);
  embed_proj_kernel<<<(BB * LT) / 32, 256, 0, stream>>>(y, dec_emb, dec_Wk, dec_b, xz_dec);

  // encoder LSTM (h0=c0=0): 128 WGs x 512 threads
  lstm_kernel<<<NSL * BB, 512, 0, stream>>>(
      xz_enc, enc_Wr, nullptr, 0, nullptr, Henc, c_fin, nmb, fmb, 0, LS);

  // decoder LSTM (h0 = enc final h rows inside Henc, c0 = c_fin)
  lstm_kernel<<<NSL * BB, 512, 0, stream>>>(
      xz_dec, dec_Wr, Henc + (size_t)(LS - 1) * HID, LS * HID, c_fin,
      S, nullptr, nmb, fmb, 1, LT);

  // attention + bf16 feat pack
  attn_kernel<<<BB * LT, 256, 0, stream>>>(Henc, S, featB);

  // prepack Wout -> transposed bf16
  prepack_wt_kernel<<<8 * 500, 256, 0, stream>>>(Wout, WoutT);

  // GEMM + exp (unnormalized) + rowsum; then invert; then scale
  proj_exp_kernel<<<8 * 250, 256, 0, stream>>>(
      (const ushort_t*)featB, WoutT, bout, rowsum, out);
  invert_kernel<<<8, 256, 0, stream>>>(rowsum);
  scale_kernel<<<4 * BB * LT, 256, 0, stream>>>(out, rowsum);
}

// Round 7
// 1283.375 us; speedup vs baseline: 1.4878x; 1.0840x over previous
//
#include <hip/hip_runtime.h>
#include <hip/hip_bf16.h>
#include <math.h>

// Problem constants
#define BB    16
#define LS    256
#define LT    128
#define EMB   128
#define HID   256
#define G4    1024      // 4*HID
#define VOCAB 32000

// LSTM slicing: 8 slice-WGs per batch, 512 threads each.
#define NSL   8
#define XROWS 112      // LDS-staged xz steps per burst (56 KB)

typedef __attribute__((ext_vector_type(8))) short bf16x8;
typedef __attribute__((ext_vector_type(4))) float f32x4;
typedef __attribute__((ext_vector_type(4))) int   i32x4;
typedef unsigned short ushort_t;
typedef unsigned int uint_t;

__device__ inline float sigf(float x)      { return 1.0f / (1.0f + __expf(-x)); }
__device__ inline float tanhfast(float x)  { return 1.0f - 2.0f / (1.0f + __expf(2.0f * x)); }
__device__ inline ushort_t bf16_rne(float f) {
  __hip_bfloat16 h = __float2bfloat16(f);
  return *(ushort_t*)&h;
}

// ---------------------------------------------------------------------------
// Kernel 1: xz = emb[idx] @ Wk + b for BOTH enc and dec (one launch).
// blocks [0,128): enc, 32 rows each; [128,192): dec.
// ---------------------------------------------------------------------------
__global__ __launch_bounds__(256) void embed_proj_kernel(
    const int* __restrict__ x, const int* __restrict__ y,
    const float* __restrict__ eemb, const float* __restrict__ eWk,
    const float* __restrict__ eb,
    const float* __restrict__ demb, const float* __restrict__ dWk,
    const float* __restrict__ db,
    float* __restrict__ xze, float* __restrict__ xzd)
{
  const bool enc = blockIdx.x < 128;
  const int* idx = enc ? x : y;
  const float* emb = enc ? eemb : demb;
  const float* Wk  = enc ? eWk  : dWk;
  const float* bias= enc ? eb   : db;
  float* xz        = enc ? xze  : xzd;
  const int row0 = (enc ? blockIdx.x : blockIdx.x - 128) * 32;

  __shared__ float e[32][EMB];    // 16 KB
  const int tid = threadIdx.x;

  for (int i = tid; i < 32 * EMB; i += 256) {
    int r = i >> 7, k = i & 127;
    int token = idx[row0 + r];
    e[r][k] = emb[(size_t)token * EMB + k];
  }
  __syncthreads();

  float acc[4][32];
#pragma unroll
  for (int q = 0; q < 4; ++q)
#pragma unroll
    for (int r = 0; r < 32; ++r) acc[q][r] = 0.0f;

  for (int k = 0; k < EMB; ++k) {
    float w0 = Wk[(size_t)k * G4 + 0 * 256 + tid];
    float w1 = Wk[(size_t)k * G4 + 1 * 256 + tid];
    float w2 = Wk[(size_t)k * G4 + 2 * 256 + tid];
    float w3 = Wk[(size_t)k * G4 + 3 * 256 + tid];
#pragma unroll
    for (int r = 0; r < 32; ++r) {
      float ev = e[r][k];
      acc[0][r] = fmaf(ev, w0, acc[0][r]);
      acc[1][r] = fmaf(ev, w1, acc[1][r]);
      acc[2][r] = fmaf(ev, w2, acc[2][r]);
      acc[3][r] = fmaf(ev, w3, acc[3][r]);
    }
  }
#pragma unroll
  for (int q = 0; q < 4; ++q) {
    float bb = bias[q * 256 + tid];
#pragma unroll
    for (int r = 0; r < 32; ++r)
      xz[(size_t)(row0 + r) * G4 + q * 256 + tid] = acc[q][r] + bb;
  }
}

// ---------------------------------------------------------------------------
// Kernel 2: LSTM recurrence, 8 slice-WGs per batch (128 WGs x 512 threads).
// Protocol identical to R6 (proven): dual near(sc0)/far(sc0 sc1) checksummed
// mailbox chunks {h0,h1,h0^h1^stamp,0}, stamp=(t+1)|(kid<<20), slot parity
// t&1 (max-skew-1 lattice makes reuse safe), consumer alternates near/far
// polls — forward progress never depends on the near path.
// NEW vs R6: the post-pointwise barrier is GONE. part[] is parity
// double-buffered; producer issues stores without waiting and goes straight
// into its poll, whose vmcnt(0) drains the stores concurrently with the
// poll round-trip (overlapping ~900cy far-store latency that R6 serialized).
// Race-freedom: part[p] is rewritten at step t+2 only after barrier(t+1),
// which wave0 only passes after finishing its reads of part[p] at step t.
// xbuf overwrite at burst boundaries is fenced by an extra barrier there.
// ---------------------------------------------------------------------------
__global__ __launch_bounds__(512, 1) void lstm_kernel(
    const float* __restrict__ xz,    // [B*T, 1024]
    const float* __restrict__ Wr,    // [256, 1024]
    const float* __restrict__ h0,    // null => zeros; row stride h0_stride
    int h0_stride,
    const float* __restrict__ cinit, // null => zeros; [B,256]
    float* __restrict__ Hout,        // [B*T, 256]
    float* __restrict__ c_fin,       // [B, 256] or null
    i32x4* __restrict__ nmb,         // near mailbox [B*2*128], zeroed
    i32x4* __restrict__ fmb,         // far  mailbox [B*2*128], zeroed
    int kid,                         // 0=enc, 1=dec (stamp tag)
    int T)
{
  const int b    = blockIdx.x & (BB - 1);
  const int s    = blockIdx.x >> 4;
  const int tid  = threadIdx.x;
  const int lane = tid & 63;
  const int quarter = tid >> 7;        // 0..3 : h-dim range quarter*64..+64
  const int col  = tid & 127;          // gate col within slice
  const int gate = col >> 5, u = col & 31;

  __shared__ float part[2][4][128];    // 4 KB, parity double-buffered
  __shared__ float xbuf[XROWS][128];   // 56 KB staged xz rows

  // weight column slice in registers
  float w_r[64];
  {
    const float* wp = Wr + (size_t)(quarter * 64) * G4 + gate * 256 + s * 32 + u;
#pragma unroll
    for (int j = 0; j < 64; ++j) w_r[j] = wp[(size_t)j * G4];
  }

  const int i0 = quarter * 64 + lane;
  float hv = 0.0f;
  if (h0) hv = h0[(size_t)b * h0_stride + i0];

  float cs0 = 0.0f, cs1 = 0.0f;
  if (tid < 16 && cinit) {
    cs0 = cinit[b * HID + s * 32 + 2 * tid];
    cs1 = cinit[b * HID + s * 32 + 2 * tid + 1];
  }

  const int c0i = i0 >> 1;   // mailbox chunk holding h[i0]
  const int sel = i0 & 1;

  int tp = XROWS;
  for (int t = 0; t < T; ++t, ++tp) {
    // ---- periodic xz burst into LDS (fenced both sides) ----
    if (tp >= XROWS) {
      __syncthreads();               // all readers of old xbuf are done
      tp = 0;
      for (int tt = quarter; tt < XROWS; tt += 4) {
        int ts = t + tt;
        if (ts < T)
          xbuf[tt][col] = xz[((size_t)b * T + ts) * G4 + gate * 256 + s * 32 + u];
      }
    }

    // ---- partial dot over this quarter's 64 h values (4 chains) ----
    float a0 = 0.0f, a1 = 0.0f, a2 = 0.0f, a3 = 0.0f;
#pragma unroll
    for (int j = 0; j < 64; j += 4) {
      a0 = fmaf(__int_as_float(__builtin_amdgcn_readlane(__float_as_int(hv), j + 0)), w_r[j + 0], a0);
      a1 = fmaf(__int_as_float(__builtin_amdgcn_readlane(__float_as_int(hv), j + 1)), w_r[j + 1], a1);
      a2 = fmaf(__int_as_float(__builtin_amdgcn_readlane(__float_as_int(hv), j + 2)), w_r[j + 2], a2);
      a3 = fmaf(__int_as_float(__builtin_amdgcn_readlane(__float_as_int(hv), j + 3)), w_r[j + 3], a3);
    }
    part[t & 1][quarter][col] = (a0 + a1) + (a2 + a3);
    __syncthreads();                 // the ONE per-step barrier

    const int stamp = (t + 1) | (kid << 20);
    const size_t slot = (size_t)(b * 2 + (t & 1)) * 128;

    // ---- pointwise (wave0 lanes 0..15): publish, NO wait ----
    if (tid < 16) {
      const int ua = 2 * tid, ub = ua + 1;
      const float (*pp)[128] = part[t & 1];
      float p0a = pp[0][ua] + pp[1][ua] + pp[2][ua] + pp[3][ua];
      float p0b = pp[0][ub] + pp[1][ub] + pp[2][ub] + pp[3][ub];
      float p1a = pp[0][32 + ua] + pp[1][32 + ua] + pp[2][32 + ua] + pp[3][32 + ua];
      float p1b = pp[0][32 + ub] + pp[1][32 + ub] + pp[2][32 + ub] + pp[3][32 + ub];
      float p2a = pp[0][64 + ua] + pp[1][64 + ua] + pp[2][64 + ua] + pp[3][64 + ua];
      float p2b = pp[0][64 + ub] + pp[1][64 + ub] + pp[2][64 + ub] + pp[3][64 + ub];
      float p3a = pp[0][96 + ua] + pp[1][96 + ua] + pp[2][96 + ua] + pp[3][96 + ua];
      float p3b = pp[0][96 + ub] + pp[1][96 + ub] + pp[2][96 + ub] + pp[3][96 + ub];
      float2 xg0 = *(const float2*)&xbuf[tp][ua];
      float2 xg1 = *(const float2*)&xbuf[tp][32 + ua];
      float2 xg2 = *(const float2*)&xbuf[tp][64 + ua];
      float2 xg3 = *(const float2*)&xbuf[tp][96 + ua];

      float zi0 = p0a + xg0.x, zi1 = p0b + xg0.y;
      float zf0 = p1a + xg1.x, zf1 = p1b + xg1.y;
      float zg0 = p2a + xg2.x, zg1 = p2b + xg2.y;
      float zo0 = p3a + xg3.x, zo1 = p3b + xg3.y;

      cs0 = fmaf(sigf(zf0), cs0, sigf(zi0) * tanhfast(zg0));
      cs1 = fmaf(sigf(zf1), cs1, sigf(zi1) * tanhfast(zg1));
      float ha = sigf(zo0) * tanhfast(cs0);
      float hb = sigf(zo1) * tanhfast(cs1);

      *(float2*)&Hout[((size_t)b * T + t) * HID + s * 32 + ua] = make_float2(ha, hb);

      i32x4 ch;
      ch.x = __float_as_int(ha);
      ch.y = __float_as_int(hb);
      ch.z = ch.x ^ ch.y ^ stamp;
      ch.w = 0;
      const i32x4* nd = nmb + slot + s * 16 + tid;
      const i32x4* fd = fmb + slot + s * 16 + tid;
      asm volatile("global_store_dwordx4 %0, %1, off sc0"
                   :: "v"(nd), "v"(ch) : "memory");
      asm volatile("global_store_dwordx4 %0, %1, off sc0 sc1"
                   :: "v"(fd), "v"(ch) : "memory");
    }
    // NO barrier here: store drain overlaps with the poll round-trip below.

    // ---- poll h(t): near (L2) attempt, then far (LLC) attempt, repeat ----
    if (t + 1 < T) {
      const i32x4* np = nmb + slot + c0i;
      const i32x4* fp = fmb + slot + c0i;
      i32x4 v;
      for (;;) {
        asm volatile("global_load_dwordx4 %0, %1, off sc0\n\t"
                     "s_waitcnt vmcnt(0)"
                     : "=&v"(v) : "v"(np) : "memory");
        if (v.z == (v.x ^ v.y ^ stamp)) break;
        asm volatile("global_load_dwordx4 %0, %1, off sc0 sc1\n\t"
                     "s_waitcnt vmcnt(0)"
                     : "=&v"(v) : "v"(fp) : "memory");
        if (v.z == (v.x ^ v.y ^ stamp)) break;
      }
      hv = __int_as_float(sel ? v.y : v.x);
    }
  }
  if (c_fin && tid < 16)
    *(float2*)&c_fin[b * HID + s * 32 + 2 * tid] = make_float2(cs0, cs1);
}

// ---------------------------------------------------------------------------
// Kernel 3 (merged): blocks [0,4000): prepack WoutT[n][k] = bf16(Wout[k][n]);
// blocks [4000,6048): attention + bf16 feat pack.
// ---------------------------------------------------------------------------
__global__ __launch_bounds__(256) void mid_kernel(
    const float* __restrict__ W, ushort_t* __restrict__ WT,
    const float* __restrict__ Henc, const float* __restrict__ S,
    __hip_bfloat16* __restrict__ featB)
{
  const int tid = threadIdx.x;

  if (blockIdx.x < 4000) {
    // ---------------- prepack ----------------
    __shared__ float tile[64][65];
    const int nt = blockIdx.x % 500;
    const int kt = blockIdx.x / 500;
    const int n0 = nt * 64, k0 = kt * 64;
    const int r = tid >> 6, c = tid & 63;

#pragma unroll
    for (int q = 0; q < 16; ++q) {
      int kk = q * 4 + r;
      tile[kk][c] = W[(size_t)(k0 + kk) * VOCAB + n0 + c];
    }
    __syncthreads();

    const int nl = tid >> 2;             // 0..63 output row
    const int seg = (tid & 3) * 16;      // 16 k per thread
    uint_t o[8];
#pragma unroll
    for (int j = 0; j < 8; ++j) {
      uint_t lo = bf16_rne(tile[seg + 2 * j][nl]);
      uint_t hi = bf16_rne(tile[seg + 2 * j + 1][nl]);
      o[j] = lo | (hi << 16);
    }
    ushort_t* dst = WT + (size_t)(n0 + nl) * 512 + k0 + seg;
    ((uint4*)dst)[0] = make_uint4(o[0], o[1], o[2], o[3]);
    ((uint4*)dst)[1] = make_uint4(o[4], o[5], o[6], o[7]);
  } else {
    // ---------------- attention ----------------
    __shared__ float srow[HID];
    __shared__ float p[LS];
    __shared__ float sm[LS];

    const int m = blockIdx.x - 4000;   // b*LT + t
    const int b = m >> 7, t = m & (LT - 1);

    const float* s_ = (t == 0) ? (Henc + ((size_t)b * LS + (LS - 1)) * HID)
                               : (S + (size_t)(m - 1) * HID);
    srow[tid] = s_[tid];
    __syncthreads();

    const float4* h4 = (const float4*)(Henc + ((size_t)b * LS + tid) * HID);
    const float4* s4 = (const float4*)srow;
    float sc = 0.0f;
#pragma unroll 8
    for (int k = 0; k < HID / 4; ++k) {
      float4 a = h4[k], q = s4[k];
      sc += a.x * q.x + a.y * q.y + a.z * q.z + a.w * q.w;
    }
    sm[tid] = sc;
    __syncthreads();
    for (int st = 128; st > 0; st >>= 1) {
      if (tid < st) sm[tid] = fmaxf(sm[tid], sm[tid + st]);
      __syncthreads();
    }
    float mx = sm[0];
    __syncthreads();
    float e = __expf(sc - mx);
    p[tid] = e;
    sm[tid] = e;
    __syncthreads();
    for (int st = 128; st > 0; st >>= 1) {
      if (tid < st) sm[tid] += sm[tid + st];
      __syncthreads();
    }
    float inv = 1.0f / sm[0];

    float a_d = 0.0f;
#pragma unroll 4
    for (int s2 = 0; s2 < LS; ++s2)
      a_d = fmaf(p[s2], Henc[((size_t)b * LS + s2) * HID + tid], a_d);
    a_d *= inv;

    featB[(size_t)m * (2 * HID) + tid]       = __float2bfloat16(S[(size_t)m * HID + tid]);
    featB[(size_t)m * (2 * HID) + HID + tid] = __float2bfloat16(a_d);
  }
}

// ---------------------------------------------------------------------------
// GEMM core: 256x128 tile, 4 waves (2x2), wave tile 128x64, direct loads.
// ---------------------------------------------------------------------------
__device__ inline void gemm_tile(
    const ushort_t* __restrict__ A, const ushort_t* __restrict__ BT,
    f32x4 (&acc)[8][4], int m0, int n0, int r, int kg)
{
#pragma unroll
  for (int i = 0; i < 8; ++i)
#pragma unroll
    for (int j = 0; j < 4; ++j) acc[i][j] = (f32x4){0.f, 0.f, 0.f, 0.f};

  for (int ks = 0; ks < 16; ++ks) {
    const int kb = ks * 32 + kg * 8;
    bf16x8 a[8], bb[4];
#pragma unroll
    for (int i = 0; i < 8; ++i)
      a[i] = *(const bf16x8*)(A + (size_t)(m0 + i * 16 + r) * 512 + kb);
#pragma unroll
    for (int j = 0; j < 4; ++j)
      bb[j] = *(const bf16x8*)(BT + (size_t)(n0 + j * 16 + r) * 512 + kb);
#pragma unroll
    for (int i = 0; i < 8; ++i)
#pragma unroll
      for (int j = 0; j < 4; ++j)
        acc[i][j] = __builtin_amdgcn_mfma_f32_16x16x32_bf16(a[i], bb[j], acc[i][j], 0, 0, 0);
  }
}

// Kernel 4: GEMM -> E = exp(logit) written unnormalized + rowsum atomics.
__global__ __launch_bounds__(256) void proj_exp_kernel(
    const ushort_t* __restrict__ A, const ushort_t* __restrict__ BT,
    const float* __restrict__ bout, float* __restrict__ rowsum,
    float* __restrict__ out)
{
  const int k2 = (blockIdx.x & 7) * 250 + (blockIdx.x >> 3);  // XCD-chunked
  const int nt = k2 >> 3;     // 0..249
  const int mt = k2 & 7;      // 0..7
  const int wave = threadIdx.x >> 6, lane = threadIdx.x & 63;
  const int wm = wave >> 1, wn = wave & 1;
  const int r = lane & 15, kg = lane >> 4;
  const int m0 = mt * 256 + wm * 128;
  const int n0 = nt * 128 + wn * 64;

  f32x4 acc[8][4];
  gemm_tile(A, BT, acc, m0, n0, r, kg);

  float bv[4];
#pragma unroll
  for (int j = 0; j < 4; ++j) bv[j] = bout[n0 + j * 16 + r];

#pragma unroll
  for (int i = 0; i < 8; ++i)
#pragma unroll
    for (int q = 0; q < 4; ++q) {
      const int row = m0 + i * 16 + kg * 4 + q;
      float v = 0.0f;
#pragma unroll
      for (int j = 0; j < 4; ++j) {
        float e = __expf(acc[i][j][q] + bv[j]);
        out[(size_t)row * VOCAB + n0 + j * 16 + r] = e;
        v += e;
      }
#pragma unroll
      for (int msk = 1; msk < 16; msk <<= 1) v += __shfl_xor(v, msk, 64);
      if (r == 0) atomicAdd(&rowsum[row], v);
    }
}

// Kernel 5: out *= 1/rowsum[row]  (invert folded in). 4 blocks per row.
__global__ __launch_bounds__(256) void scale_kernel(
    float* __restrict__ out, const float* __restrict__ rowsum)
{
  const int row = blockIdx.x >> 2;       // 0..2047
  const int seg = blockIdx.x & 3;        // 4 segments of 2000 float4
  const float s = 1.0f / rowsum[row];
  float4* o4 = (float4*)(out + (size_t)row * VOCAB) + seg * 2000;
  for (int i = threadIdx.x; i < 2000; i += 256) {
    float4 v = o4[i];
    v.x *= s; v.y *= s; v.z *= s; v.w *= s;
    o4[i] = v;
  }
}

// ---------------------------------------------------------------------------
// Host launcher
// ---------------------------------------------------------------------------
extern "C" void kernel_launch(void* const* d_in, const int* in_sizes, int n_in,
                              void* d_out, int out_size, void* d_ws, size_t ws_size,
                              hipStream_t stream) {
  (void)in_sizes; (void)n_in; (void)out_size; (void)ws_size;

  const int*   x       = (const int*)d_in[0];
  const int*   y       = (const int*)d_in[1];
  const float* enc_emb = (const float*)d_in[2];
  const float* enc_Wk  = (const float*)d_in[3];
  const float* enc_Wr  = (const float*)d_in[4];
  const float* enc_b   = (const float*)d_in[5];
  const float* dec_emb = (const float*)d_in[6];
  const float* dec_Wk  = (const float*)d_in[7];
  const float* dec_Wr  = (const float*)d_in[8];
  const float* dec_b   = (const float*)d_in[9];
  const float* Wout    = (const float*)d_in[10];
  const float* bout    = (const float*)d_in[11];
  float* out = (float*)d_out;
  char*  ws  = (char*)d_ws;

  // workspace layout (bytes); rowsum+nmb+fmb contiguous -> ONE memset
  size_t off = 0;
  float* xz_enc = (float*)(ws + off); off += (size_t)BB * LS * G4 * 4;      // 16 MB
  float* xz_dec = (float*)(ws + off); off += (size_t)BB * LT * G4 * 4;      //  8 MB
  float* Henc   = (float*)(ws + off); off += (size_t)BB * LS * HID * 4;     //  4 MB
  float* S      = (float*)(ws + off); off += (size_t)BB * LT * HID * 4;     //  2 MB
  __hip_bfloat16* featB = (__hip_bfloat16*)(ws + off);
  off += (size_t)BB * LT * 2 * HID * 2;                                     //  2 MB
  ushort_t* WoutT = (ushort_t*)(ws + off); off += (size_t)VOCAB * 512 * 2;  // 32 MB
  float* c_fin  = (float*)(ws + off); off += (size_t)BB * HID * 4;
  size_t zero_base = off;
  float* rowsum = (float*)(ws + off); off += (size_t)BB * LT * 4;           //  8 KB
  i32x4* nmb    = (i32x4*)(ws + off); off += (size_t)BB * 2 * 128 * 16;     // 64 KB
  i32x4* fmb    = (i32x4*)(ws + off); off += (size_t)BB * 2 * 128 * 16;     // 64 KB
  size_t zero_len = off - zero_base;

  hipMemsetAsync(ws + zero_base, 0, zero_len, stream);

  // input projections (enc + dec in one launch)
  embed_proj_kernel<<<192, 256, 0, stream>>>(
      x, y, enc_emb, enc_Wk, enc_b, dec_emb, dec_Wk, dec_b, xz_enc, xz_dec);

  // encoder LSTM (h0=c0=0): 128 WGs x 512 threads
  lstm_kernel<<<NSL * BB, 512, 0, stream>>>(
      xz_enc, enc_Wr, nullptr, 0, nullptr, Henc, c_fin, nmb, fmb, 0, LS);

  // decoder LSTM (h0 = enc final h rows inside Henc, c0 = c_fin)
  lstm_kernel<<<NSL * BB, 512, 0, stream>>>(
      xz_dec, dec_Wr, Henc + (size_t)(LS - 1) * HID, LS * HID, c_fin,
      S, nullptr, nmb, fmb, 1, LT);

  // prepack + attention in one launch
  mid_kernel<<<4000 + BB * LT, 256, 0, stream>>>(
      Wout, WoutT, Henc, S, (__hip_bfloat16*)featB);

  // GEMM + exp (unnormalized) + rowsum; then scale (invert folded)
  proj_exp_kernel<<<8 * 250, 256, 0, stream>>>(
      (const ushort_t*)featB, WoutT, bout, rowsum, out);
  scale_kernel<<<4 * BB * LT, 256, 0, stream>>>(out, rowsum);
}